// Round 12
// baseline (201.134 us; speedup 1.0000x reference)
//
#include <hip/hip_runtime.h>

typedef _Float16 half_t;
typedef _Float16 half2_t __attribute__((ext_vector_type(2)));
typedef _Float16 half4_t __attribute__((ext_vector_type(4)));
typedef _Float16 half8 __attribute__((ext_vector_type(8)));
typedef float f32x4 __attribute__((ext_vector_type(4)));
typedef float f32x16 __attribute__((ext_vector_type(16)));
typedef unsigned uint4v __attribute__((ext_vector_type(4)));

__device__ __forceinline__ void gload_lds16(const void* g, void* l) {
    __builtin_amdgcn_global_load_lds(
        (const __attribute__((address_space(1))) void*)g,
        (__attribute__((address_space(3))) void*)l, 16, 0, 0);
}

// ---------------- cast fp32 -> fp16 (x) ----------------
__global__ __launch_bounds__(256) void cast_f32_f16(const float* __restrict__ s,
                                                    half_t* __restrict__ d, int n) {
    const int stride = gridDim.x * blockDim.x;
    for (int i = blockIdx.x * blockDim.x + threadIdx.x; i * 4 < n; i += stride) {
        const float4 v = *(const float4*)(s + (long)i * 4);
        half4_t h = {(half_t)v.x, (half_t)v.y, (half_t)v.z, (half_t)v.w};
        *(half4_t*)(d + (long)i * 4) = h;
    }
}

// ---------------- cast 4 weight matrices + concat bias (merged) ----------------
__global__ __launch_bounds__(256) void cast_w4b(const float* __restrict__ w0,
                                                const float* __restrict__ w1,
                                                const float* __restrict__ w2,
                                                const float* __restrict__ w3,
                                                const float* __restrict__ b0,
                                                const float* __restrict__ b1,
                                                const float* __restrict__ b2,
                                                half_t* __restrict__ d,
                                                float* __restrict__ bc) {
    const int i = blockIdx.x * blockDim.x + threadIdx.x;   // float4 index
    const int which = i / 147456;                          // 768*768/4
    const int off = i - which * 147456;
    const float* s = which == 0 ? w0 : which == 1 ? w1 : which == 2 ? w2 : w3;
    const float4 v = *(const float4*)(s + (long)off * 4);
    half4_t h = {(half_t)v.x, (half_t)v.y, (half_t)v.z, (half_t)v.w};
    *(half4_t*)(d + (long)i * 4) = h;
    if (i < 2304) bc[i] = i < 768 ? b0[i] : i < 1536 ? b1[i - 768] : b2[i - 1536];
}

// ---------------- GEMM: 128x128 tile, BK=32, 2-buf, 5 blocks/CU ----------------
// C[8192,N] = A[8192,768] * W[N,768]^T + bias.  K=768 -> NT=24 K-tiles of 32.
// 32 KiB LDS (2 bufs x (A 8K + B 8K)) -> 5 blocks/CU (launch_bounds(256,5)).
// QKV grid 64x18 = 1152 blocks ALL co-resident (1280 slots) -> zero tail; TLP
// (20 waves/CU) hides stage latency cross-block (m114) instead of deep
// pipelining.  Coalesced staging: 4 lanes per 64B row-segment; chunk-XOR
// c^((row>>1)&3) on BOTH stage-source and ds_read -> 2-way bank alias (free).
// One barrier per phase (STAGE targets the buffer whose previous-phase reads
// were consumed by MFMA before the barrier - ledger-checked).
// VSPLIT: N-tiles >=12 (cols 1536..2303 = V) are written TRANSPOSED into Vt.
template <typename OutT, bool VSPLIT>
__global__ __launch_bounds__(256, 5) void gemm5(const half_t* __restrict__ A,
                                                const half_t* __restrict__ W,
                                                const float* __restrict__ bias,
                                                OutT* __restrict__ C,
                                                half_t* __restrict__ Vt,
                                                const int N) {
    constexpr int Kdim = 768, NT = 24;
    alignas(16) __shared__ half_t Ab[2][128][32];   // 16 KiB
    alignas(16) __shared__ half_t Bb[2][128][32];   // 16 KiB

    const int t = threadIdx.x, l = t & 63, wv = t >> 6;
    const int wr = wv >> 1, wc = wv & 1;             // 2M x 2N waves
    const int m0 = blockIdx.x * 128, n0 = blockIdx.y * 128;

    f32x4 acc[4][4] = {};

    const half_t* Ag = A + (long)m0 * Kdim;
    const half_t* Wg = W + (long)n0 * Kdim;

    // stage: lane l -> row base+(l>>2), phys chunk l&3 holds logical chunk
    // c = (l&3)^((row>>1)&3).  Dest is wave-uniform 1KB region (linear fill).
    auto STAGE = [&](int tile, int buf) {
        const int k0 = tile * 32;
#pragma unroll
        for (int r = 0; r < 2; ++r) {
            const int row = (wv * 2 + r) * 16 + (l >> 2);
            const int c = (l & 3) ^ ((row >> 1) & 3);
            gload_lds16(Ag + (long)row * Kdim + k0 + c * 8,
                        &Ab[buf][(wv * 2 + r) * 16][0]);
            gload_lds16(Wg + (long)row * Kdim + k0 + c * 8,
                        &Bb[buf][(wv * 2 + r) * 16][0]);
        }
    };

    STAGE(0, 0);

    for (int p = 0; p < NT; ++p) {
        const int buf = p & 1;
        asm volatile("s_waitcnt vmcnt(0)" ::: "memory");
        __builtin_amdgcn_s_barrier();
        asm volatile("" ::: "memory");

        const int kq = l >> 4;                       // logical k-chunk 0..3
        half8 afr[4], bfr[4];
#pragma unroll
        for (int i = 0; i < 4; ++i) {
            const int ar = wr * 64 + i * 16 + (l & 15);
            afr[i] = *(const half8*)&Ab[buf][ar][(kq ^ ((ar >> 1) & 3)) * 8];
            const int br = wc * 64 + i * 16 + (l & 15);
            bfr[i] = *(const half8*)&Bb[buf][br][(kq ^ ((br >> 1) & 3)) * 8];
        }

        if (p + 1 < NT) STAGE(p + 1, buf ^ 1);

        __builtin_amdgcn_s_setprio(1);
#pragma unroll
        for (int mi = 0; mi < 4; ++mi)
#pragma unroll
            for (int ni = 0; ni < 4; ++ni)
                acc[mi][ni] = __builtin_amdgcn_mfma_f32_16x16x32_f16(
                    afr[mi], bfr[ni], acc[mi][ni], 0, 0, 0);
        __builtin_amdgcn_s_setprio(0);
    }

    // ---- epilogue ----
    const bool vtile = VSPLIT && (blockIdx.y >= 12);     // pure-V N-tiles
#pragma unroll
    for (int ni = 0; ni < 4; ++ni) {
        const int col = n0 + wc * 64 + ni * 16 + (l & 15);
        const float bb = bias[col];
        if (!vtile) {
#pragma unroll
            for (int mi = 0; mi < 4; ++mi) {
                const int row = m0 + wr * 64 + mi * 16 + (l >> 4) * 4;
#pragma unroll
                for (int r = 0; r < 4; ++r)
                    C[(long)(row + r) * N + col] = (OutT)(acc[mi][ni][r] + bb);
            }
        } else {
            const int hd = col - 1536;
            const int hidx = hd >> 6, d = hd & 63;
#pragma unroll
            for (int mi = 0; mi < 4; ++mi) {
                const int row = m0 + wr * 64 + mi * 16 + (l >> 4) * 4;
                const int b = row >> 10, n = row & 1023;
                half4_t pk;
#pragma unroll
                for (int r = 0; r < 4; ++r) pk[r] = (half_t)(acc[mi][ni][r] + bb);
                *(half4_t*)(Vt + ((long)((b * 12 + hidx) * 64 + d)) * 1024 + n) = pk;
            }
        }
    }
}

// ---------------- flash attention v5 (unchanged) ----------------
__global__ __launch_bounds__(256) void attn5_kernel(const half_t* __restrict__ qkv,
                                                    const half_t* __restrict__ Vt,
                                                    const float* __restrict__ head_mask,
                                                    half_t* __restrict__ Y) {
    alignas(16) __shared__ half_t Kl[2][64 * 64];
    alignas(16) __shared__ half_t Vl[2][64 * 64];

    const int t = threadIdx.x, l = t & 63, wv = t >> 6;
    const int h2 = l >> 5, q32 = l & 31;
    const int bh = blockIdx.x, b = bh / 12, hh = bh % 12;
    const int q0 = blockIdx.y * 128 + wv * 32;

    half8 qf[4];
    {
        const half_t SC = (half_t)(0.125f * 1.44269504f);
        const half_t* Qp = qkv + ((long)(b * 1024 + q0 + q32)) * 2304 + hh * 64 + h2 * 8;
#pragma unroll
        for (int kd = 0; kd < 4; ++kd) {
            half8 v = *(const half8*)(Qp + kd * 16);
#pragma unroll
            for (int j = 0; j < 8; ++j) v[j] = v[j] * SC;
            qf[kd] = v;
        }
    }

    const half8 ONES = {(half_t)1, (half_t)1, (half_t)1, (half_t)1,
                        (half_t)1, (half_t)1, (half_t)1, (half_t)1};

    const half_t* Kg = qkv + (long)b * 1024 * 2304 + 768 + hh * 64;
    const half_t* Vg = Vt + (long)bh * 64 * 1024;

    const int srow_lo = (l >> 3);
    const int schunk = l & 7;

    auto STAGE = [&](int tile, int bf) {
#pragma unroll
        for (int c = 0; c < 2; ++c) {
            const int row = c * 32 + wv * 8 + srow_lo;
            const int sc_ = (schunk ^ (row & 7)) * 8;
            gload_lds16(Kg + (long)(tile * 64 + row) * 2304 + sc_,
                        &Kl[bf][(c * 32 + wv * 8) * 64]);
            gload_lds16(Vg + (long)row * 1024 + tile * 64 + sc_,
                        &Vl[bf][(c * 32 + wv * 8) * 64]);
        }
    };

    f32x16 o0 = {}, o1 = {}, lacc = {};

    STAGE(0, 0);

    for (int tt = 0; tt < 16; ++tt) {
        const int bf = tt & 1;
        if (tt < 15) {
            STAGE(tt + 1, bf ^ 1);
            asm volatile("s_waitcnt vmcnt(4)" ::: "memory");
        } else {
            asm volatile("s_waitcnt vmcnt(0)" ::: "memory");
        }
        __builtin_amdgcn_s_barrier();
        asm volatile("" ::: "memory");

        f32x16 s0 = {}, s1 = {};
        __builtin_amdgcn_s_setprio(1);
#pragma unroll
        for (int kd = 0; kd < 4; ++kd) {
            const int ch = ((kd * 2 + h2) ^ (q32 & 7)) * 8;
            half8 k0 = *(const half8*)&Kl[bf][q32 * 64 + ch];
            half8 k1 = *(const half8*)&Kl[bf][(32 + q32) * 64 + ch];
            s0 = __builtin_amdgcn_mfma_f32_32x32x16_f16(k0, qf[kd], s0, 0, 0, 0);
            s1 = __builtin_amdgcn_mfma_f32_32x32x16_f16(k1, qf[kd], s1, 0, 0, 0);
        }
        __builtin_amdgcn_s_setprio(0);

#pragma unroll
        for (int kc = 0; kc < 4; ++kc) {
            const f32x16& ss = (kc >> 1) ? s1 : s0;
            const int rb = (kc & 1) * 8;
            unsigned pw[4];
#pragma unroll
            for (int k2 = 0; k2 < 4; ++k2) {
                const float a = __builtin_amdgcn_exp2f(ss[rb + 2 * k2]);
                const float c = __builtin_amdgcn_exp2f(ss[rb + 2 * k2 + 1]);
                pw[k2] = __builtin_bit_cast(unsigned, __builtin_amdgcn_cvt_pkrtz(a, c));
            }
            uint4v uu = {pw[0], pw[1], pw[2], pw[3]};
            const half8 pf = __builtin_bit_cast(half8, uu);

            const int g0 = 2 * kc;
            const int a0 = q32 * 64 + ((g0 ^ (q32 & 7)) * 8) + 4 * h2;
            const int a1 = q32 * 64 + (((g0 + 1) ^ (q32 & 7)) * 8) + 4 * h2;
            const int r2 = 32 + q32;
            const int b0 = r2 * 64 + ((g0 ^ (r2 & 7)) * 8) + 4 * h2;
            const int b1 = r2 * 64 + (((g0 + 1) ^ (r2 & 7)) * 8) + 4 * h2;
            half4_t va0 = *(const half4_t*)&Vl[bf][a0];
            half4_t va1 = *(const half4_t*)&Vl[bf][a1];
            half4_t vb0 = *(const half4_t*)&Vl[bf][b0];
            half4_t vb1 = *(const half4_t*)&Vl[bf][b1];
            half8 vf0 = {va0[0], va0[1], va0[2], va0[3], va1[0], va1[1], va1[2], va1[3]};
            half8 vf1 = {vb0[0], vb0[1], vb0[2], vb0[3], vb1[0], vb1[1], vb1[2], vb1[3]};

            __builtin_amdgcn_s_setprio(1);
            o0 = __builtin_amdgcn_mfma_f32_32x32x16_f16(vf0, pf, o0, 0, 0, 0);
            o1 = __builtin_amdgcn_mfma_f32_32x32x16_f16(vf1, pf, o1, 0, 0, 0);
            lacc = __builtin_amdgcn_mfma_f32_32x32x16_f16(ONES, pf, lacc, 0, 0, 0);
            __builtin_amdgcn_s_setprio(0);
        }

        asm volatile("" ::: "memory");
        __builtin_amdgcn_s_barrier();
    }

    const float hmv = head_mask[b * 12 + hh];
    const float sc = hmv * hmv / lacc[0];
    half_t* Yp = Y + ((long)(b * 1024 + q0 + q32)) * 768 + hh * 64;
#pragma unroll
    for (int db = 0; db < 2; ++db) {
        const f32x16 oo = db ? o1 : o0;
#pragma unroll
        for (int rq = 0; rq < 4; ++rq) {
            half4_t pk;
#pragma unroll
            for (int i = 0; i < 4; ++i) pk[i] = (half_t)(oo[rq * 4 + i] * sc);
            *(half4_t*)(Yp + db * 32 + rq * 8 + h2 * 4) = pk;
        }
    }
}

// ---------------- launch ----------------
extern "C" void kernel_launch(void* const* d_in, const int* in_sizes, int n_in,
                              void* d_out, int out_size, void* d_ws, size_t ws_size,
                              hipStream_t stream) {
    const float* x   = (const float*)d_in[0];
    const float* hm  = (const float*)d_in[1];
    const float* q_w = (const float*)d_in[2];
    const float* q_b = (const float*)d_in[3];
    const float* k_w = (const float*)d_in[4];
    const float* k_b = (const float*)d_in[5];
    const float* v_w = (const float*)d_in[6];
    const float* v_b = (const float*)d_in[7];
    const float* p_w = (const float*)d_in[8];
    const float* p_b = (const float*)d_in[9];
    float* out = (float*)d_out;

    char* ws = (char*)d_ws;
    half_t* xh  = (half_t*)(ws);                    // 8192*768*2   = 12582912
    half_t* wc  = (half_t*)(ws + 12582912);         // [qkv|proj] weights fp16
    half_t* pwh = (half_t*)(ws + 16121856);         //   (proj part of wc)
    float*  bc  = (float*)(ws + 17301504);          // 2304*4
    half_t* qkv = (half_t*)(ws + 17310720);         // 8192*2304*2  = 37748736
    half_t* y   = (half_t*)(ws + 55059456);         // 8192*768*2   = 12582912
    half_t* Vt = (ws_size >= (size_t)67642368 + 12582912)
                     ? (half_t*)(ws + 67642368)
                     : (half_t*)d_out;

    cast_f32_f16<<<2048, 256, 0, stream>>>(x, xh, 8192 * 768);
    cast_w4b<<<2304, 256, 0, stream>>>(q_w, k_w, v_w, p_w, q_b, k_b, v_b, wc, bc);

    gemm5<half_t, true><<<dim3(64, 18), 256, 0, stream>>>(xh, wc, bc, qkv, Vt, 2304);
    attn5_kernel<<<dim3(96, 8), 256, 0, stream>>>(qkv, Vt, hm, y);
    gemm5<float, false><<<dim3(64, 6), 256, 0, stream>>>(y, pwh, p_b, out, nullptr, 768);
}

// Round 13
// 117.309 us; speedup vs baseline: 1.7146x; 1.7146x over previous
//
#include <hip/hip_runtime.h>

typedef _Float16 half_t;
typedef _Float16 half2_t __attribute__((ext_vector_type(2)));
typedef _Float16 half4_t __attribute__((ext_vector_type(4)));
typedef _Float16 half8 __attribute__((ext_vector_type(8)));
typedef float f32x4 __attribute__((ext_vector_type(4)));
typedef float f32x16 __attribute__((ext_vector_type(16)));
typedef unsigned uint4v __attribute__((ext_vector_type(4)));

__device__ __forceinline__ void gload_lds16(const void* g, void* l) {
    __builtin_amdgcn_global_load_lds(
        (const __attribute__((address_space(1))) void*)g,
        (__attribute__((address_space(3))) void*)l, 16, 0, 0);
}

// ---------------- cast fp32 -> fp16 (x) ----------------
__global__ __launch_bounds__(256) void cast_f32_f16(const float* __restrict__ s,
                                                    half_t* __restrict__ d, int n) {
    const int stride = gridDim.x * blockDim.x;
    for (int i = blockIdx.x * blockDim.x + threadIdx.x; i * 4 < n; i += stride) {
        const float4 v = *(const float4*)(s + (long)i * 4);
        half4_t h = {(half_t)v.x, (half_t)v.y, (half_t)v.z, (half_t)v.w};
        *(half4_t*)(d + (long)i * 4) = h;
    }
}

// ---------------- cast 4 weight matrices + concat bias (merged) ----------------
__global__ __launch_bounds__(256) void cast_w4b(const float* __restrict__ w0,
                                                const float* __restrict__ w1,
                                                const float* __restrict__ w2,
                                                const float* __restrict__ w3,
                                                const float* __restrict__ b0,
                                                const float* __restrict__ b1,
                                                const float* __restrict__ b2,
                                                half_t* __restrict__ d,
                                                float* __restrict__ bc) {
    const int i = blockIdx.x * blockDim.x + threadIdx.x;   // float4 index
    const int which = i / 147456;                          // 768*768/4
    const int off = i - which * 147456;
    const float* s = which == 0 ? w0 : which == 1 ? w1 : which == 2 ? w2 : w3;
    const float4 v = *(const float4*)(s + (long)off * 4);
    half4_t h = {(half_t)v.x, (half_t)v.y, (half_t)v.z, (half_t)v.w};
    *(half4_t*)(d + (long)i * 4) = h;
    if (i < 2304) bc[i] = i < 768 ? b0[i] : i < 1536 ? b1[i - 768] : b2[i - 1536];
}

// ---------------- GEMM: 128x128 tile, BK=32, 2-buf, high-TLP ----------------
// C[8192,N] = A[8192,768] * W[N,768]^T + bias.  K=768 -> NT=24 K-tiles of 32.
// 32 KiB LDS, NO occupancy cap (r12's launch_bounds(256,5) forced VGPR=48 <
// the 64-VGPR accumulator -> spill -> 143MB scratch writes).  Natural alloc
// (~88 VGPR) gives 5 waves/SIMD -> 5 blocks/CU: whole 1152-block QKV grid is
// co-resident, cross-block TLP hides the 2-phase stage/barrier stalls (m114).
// Coalesced staging (4 lanes x 16B per 64B row-segment); chunk-XOR
// c^((row>>1)&3) on both stage-source and ds_read -> 2-way alias (free).
// VSPLIT: N-tiles >=12 (= V) written TRANSPOSED into Vt with the PV
// permutation baked in: dst n = n with bits 2<->3 swapped (involution), so
// attention reads V fragments as single b128 chunks (same pattern as K).
template <typename OutT, bool VSPLIT>
__global__ __launch_bounds__(256) void gemm5(const half_t* __restrict__ A,
                                             const half_t* __restrict__ W,
                                             const float* __restrict__ bias,
                                             OutT* __restrict__ C,
                                             half_t* __restrict__ Vt,
                                             const int N) {
    constexpr int Kdim = 768, NT = 24;
    alignas(16) __shared__ half_t Ab[2][128][32];   // 16 KiB
    alignas(16) __shared__ half_t Bb[2][128][32];   // 16 KiB

    const int t = threadIdx.x, l = t & 63, wv = t >> 6;
    const int wr = wv >> 1, wc = wv & 1;             // 2M x 2N waves
    const int m0 = blockIdx.x * 128, n0 = blockIdx.y * 128;

    f32x4 acc[4][4] = {};

    const half_t* Ag = A + (long)m0 * Kdim;
    const half_t* Wg = W + (long)n0 * Kdim;

    auto STAGE = [&](int tile, int buf) {
        const int k0 = tile * 32;
#pragma unroll
        for (int r = 0; r < 2; ++r) {
            const int row = (wv * 2 + r) * 16 + (l >> 2);
            const int c = (l & 3) ^ ((row >> 1) & 3);
            gload_lds16(Ag + (long)row * Kdim + k0 + c * 8,
                        &Ab[buf][(wv * 2 + r) * 16][0]);
            gload_lds16(Wg + (long)row * Kdim + k0 + c * 8,
                        &Bb[buf][(wv * 2 + r) * 16][0]);
        }
    };

    STAGE(0, 0);

    for (int p = 0; p < NT; ++p) {
        const int buf = p & 1;
        asm volatile("s_waitcnt vmcnt(0)" ::: "memory");
        __builtin_amdgcn_s_barrier();
        asm volatile("" ::: "memory");

        const int kq = l >> 4;                       // logical k-chunk 0..3
        half8 afr[4], bfr[4];
#pragma unroll
        for (int i = 0; i < 4; ++i) {
            const int ar = wr * 64 + i * 16 + (l & 15);
            afr[i] = *(const half8*)&Ab[buf][ar][(kq ^ ((ar >> 1) & 3)) * 8];
            const int br = wc * 64 + i * 16 + (l & 15);
            bfr[i] = *(const half8*)&Bb[buf][br][(kq ^ ((br >> 1) & 3)) * 8];
        }

        if (p + 1 < NT) STAGE(p + 1, buf ^ 1);

        __builtin_amdgcn_s_setprio(1);
#pragma unroll
        for (int mi = 0; mi < 4; ++mi)
#pragma unroll
            for (int ni = 0; ni < 4; ++ni)
                acc[mi][ni] = __builtin_amdgcn_mfma_f32_16x16x32_f16(
                    afr[mi], bfr[ni], acc[mi][ni], 0, 0, 0);
        __builtin_amdgcn_s_setprio(0);
    }

    // ---- epilogue ----
    const bool vtile = VSPLIT && (blockIdx.y >= 12);     // pure-V N-tiles
#pragma unroll
    for (int ni = 0; ni < 4; ++ni) {
        const int col = n0 + wc * 64 + ni * 16 + (l & 15);
        const float bb = bias[col];
        if (!vtile) {
#pragma unroll
            for (int mi = 0; mi < 4; ++mi) {
                const int row = m0 + wr * 64 + mi * 16 + (l >> 4) * 4;
#pragma unroll
                for (int r = 0; r < 4; ++r)
                    C[(long)(row + r) * N + col] = (OutT)(acc[mi][ni][r] + bb);
            }
        } else {
            const int hd = col - 1536;
            const int hidx = hd >> 6, d = hd & 63;
#pragma unroll
            for (int mi = 0; mi < 4; ++mi) {
                const int row = m0 + wr * 64 + mi * 16 + (l >> 4) * 4;
                const int b = row >> 10, n = row & 1023;
                // bake PV permutation: swap bits 2<->3 of n (quad-aligned, bijective)
                const int np = (n & ~12) | ((n & 4) << 1) | ((n & 8) >> 1);
                half4_t pk;
#pragma unroll
                for (int r = 0; r < 4; ++r) pk[r] = (half_t)(acc[mi][ni][r] + bb);
                *(half4_t*)(Vt + ((long)((b * 12 + hidx) * 64 + d)) * 1024 + np) = pk;
            }
        }
    }
}

// ---------------- flash attention v6: b128 V reads (permutation pre-baked in Vt) ----------------
__global__ __launch_bounds__(256) void attn6_kernel(const half_t* __restrict__ qkv,
                                                    const half_t* __restrict__ Vt,
                                                    const float* __restrict__ head_mask,
                                                    half_t* __restrict__ Y) {
    alignas(16) __shared__ half_t Kl[2][64 * 64];
    alignas(16) __shared__ half_t Vl[2][64 * 64];

    const int t = threadIdx.x, l = t & 63, wv = t >> 6;
    const int h2 = l >> 5, q32 = l & 31;
    const int bh = blockIdx.x, b = bh / 12, hh = bh % 12;
    const int q0 = blockIdx.y * 128 + wv * 32;

    half8 qf[4];
    {
        const half_t SC = (half_t)(0.125f * 1.44269504f);
        const half_t* Qp = qkv + ((long)(b * 1024 + q0 + q32)) * 2304 + hh * 64 + h2 * 8;
#pragma unroll
        for (int kd = 0; kd < 4; ++kd) {
            half8 v = *(const half8*)(Qp + kd * 16);
#pragma unroll
            for (int j = 0; j < 8; ++j) v[j] = v[j] * SC;
            qf[kd] = v;
        }
    }

    const half8 ONES = {(half_t)1, (half_t)1, (half_t)1, (half_t)1,
                        (half_t)1, (half_t)1, (half_t)1, (half_t)1};

    const half_t* Kg = qkv + (long)b * 1024 * 2304 + 768 + hh * 64;
    const half_t* Vg = Vt + (long)bh * 64 * 1024;

    const int srow_lo = (l >> 3);
    const int schunk = l & 7;

    auto STAGE = [&](int tile, int bf) {
#pragma unroll
        for (int c = 0; c < 2; ++c) {
            const int row = c * 32 + wv * 8 + srow_lo;
            const int sc_ = (schunk ^ (row & 7)) * 8;
            gload_lds16(Kg + (long)(tile * 64 + row) * 2304 + sc_,
                        &Kl[bf][(c * 32 + wv * 8) * 64]);
            gload_lds16(Vg + (long)row * 1024 + tile * 64 + sc_,
                        &Vl[bf][(c * 32 + wv * 8) * 64]);
        }
    };

    f32x16 o0 = {}, o1 = {}, lacc = {};

    STAGE(0, 0);

    for (int tt = 0; tt < 16; ++tt) {
        const int bf = tt & 1;
        if (tt < 15) {
            STAGE(tt + 1, bf ^ 1);
            asm volatile("s_waitcnt vmcnt(4)" ::: "memory");
        } else {
            asm volatile("s_waitcnt vmcnt(0)" ::: "memory");
        }
        __builtin_amdgcn_s_barrier();
        asm volatile("" ::: "memory");

        f32x16 s0 = {}, s1 = {};
        __builtin_amdgcn_s_setprio(1);
#pragma unroll
        for (int kd = 0; kd < 4; ++kd) {
            const int ch = ((kd * 2 + h2) ^ (q32 & 7)) * 8;
            half8 k0 = *(const half8*)&Kl[bf][q32 * 64 + ch];
            half8 k1 = *(const half8*)&Kl[bf][(32 + q32) * 64 + ch];
            s0 = __builtin_amdgcn_mfma_f32_32x32x16_f16(k0, qf[kd], s0, 0, 0, 0);
            s1 = __builtin_amdgcn_mfma_f32_32x32x16_f16(k1, qf[kd], s1, 0, 0, 0);
        }
        __builtin_amdgcn_s_setprio(0);

#pragma unroll
        for (int kc = 0; kc < 4; ++kc) {
            const f32x16& ss = (kc >> 1) ? s1 : s0;
            const int rb = (kc & 1) * 8;
            unsigned pw[4];
#pragma unroll
            for (int k2 = 0; k2 < 4; ++k2) {
                const float a = __builtin_amdgcn_exp2f(ss[rb + 2 * k2]);
                const float c = __builtin_amdgcn_exp2f(ss[rb + 2 * k2 + 1]);
                pw[k2] = __builtin_bit_cast(unsigned, __builtin_amdgcn_cvt_pkrtz(a, c));
            }
            uint4v uu = {pw[0], pw[1], pw[2], pw[3]};
            const half8 pf = __builtin_bit_cast(half8, uu);

            // V fragment: single b128 per row (permuted layout baked in Vt)
            const int ch = ((2 * kc + h2) ^ (q32 & 7)) * 8;
            half8 vf0 = *(const half8*)&Vl[bf][q32 * 64 + ch];
            half8 vf1 = *(const half8*)&Vl[bf][(32 + q32) * 64 + ch];

            __builtin_amdgcn_s_setprio(1);
            o0 = __builtin_amdgcn_mfma_f32_32x32x16_f16(vf0, pf, o0, 0, 0, 0);
            o1 = __builtin_amdgcn_mfma_f32_32x32x16_f16(vf1, pf, o1, 0, 0, 0);
            lacc = __builtin_amdgcn_mfma_f32_32x32x16_f16(ONES, pf, lacc, 0, 0, 0);
            __builtin_amdgcn_s_setprio(0);
        }

        asm volatile("" ::: "memory");
        __builtin_amdgcn_s_barrier();
    }

    const float hmv = head_mask[b * 12 + hh];
    const float sc = hmv * hmv / lacc[0];
    half_t* Yp = Y + ((long)(b * 1024 + q0 + q32)) * 768 + hh * 64;
#pragma unroll
    for (int db = 0; db < 2; ++db) {
        const f32x16 oo = db ? o1 : o0;
#pragma unroll
        for (int rq = 0; rq < 4; ++rq) {
            half4_t pk;
#pragma unroll
            for (int i = 0; i < 4; ++i) pk[i] = (half_t)(oo[rq * 4 + i] * sc);
            *(half4_t*)(Yp + db * 32 + rq * 8 + h2 * 4) = pk;
        }
    }
}

// ---------------- launch ----------------
extern "C" void kernel_launch(void* const* d_in, const int* in_sizes, int n_in,
                              void* d_out, int out_size, void* d_ws, size_t ws_size,
                              hipStream_t stream) {
    const float* x   = (const float*)d_in[0];
    const float* hm  = (const float*)d_in[1];
    const float* q_w = (const float*)d_in[2];
    const float* q_b = (const float*)d_in[3];
    const float* k_w = (const float*)d_in[4];
    const float* k_b = (const float*)d_in[5];
    const float* v_w = (const float*)d_in[6];
    const float* v_b = (const float*)d_in[7];
    const float* p_w = (const float*)d_in[8];
    const float* p_b = (const float*)d_in[9];
    float* out = (float*)d_out;

    char* ws = (char*)d_ws;
    half_t* xh  = (half_t*)(ws);                    // 8192*768*2   = 12582912
    half_t* wc  = (half_t*)(ws + 12582912);         // [qkv|proj] weights fp16
    half_t* pwh = (half_t*)(ws + 16121856);         //   (proj part of wc)
    float*  bc  = (float*)(ws + 17301504);          // 2304*4
    half_t* qkv = (half_t*)(ws + 17310720);         // 8192*2304*2  = 37748736
    half_t* y   = (half_t*)(ws + 55059456);         // 8192*768*2   = 12582912
    half_t* Vt = (ws_size >= (size_t)67642368 + 12582912)
                     ? (half_t*)(ws + 67642368)
                     : (half_t*)d_out;

    cast_f32_f16<<<2048, 256, 0, stream>>>(x, xh, 8192 * 768);
    cast_w4b<<<2304, 256, 0, stream>>>(q_w, k_w, v_w, p_w, q_b, k_b, v_b, wc, bc);

    gemm5<half_t, true><<<dim3(64, 18), 256, 0, stream>>>(xh, wc, bc, qkv, Vt, 2304);
    attn6_kernel<<<dim3(96, 8), 256, 0, stream>>>(qkv, Vt, hm, y);
    gemm5<float, false><<<dim3(64, 6), 256, 0, stream>>>(y, pwh, p_b, out, nullptr, 768);
}

// Round 14
// 109.154 us; speedup vs baseline: 1.8427x; 1.0747x over previous
//
#include <hip/hip_runtime.h>

typedef _Float16 half_t;
typedef _Float16 half2_t __attribute__((ext_vector_type(2)));
typedef _Float16 half4_t __attribute__((ext_vector_type(4)));
typedef _Float16 half8 __attribute__((ext_vector_type(8)));
typedef float f32x4 __attribute__((ext_vector_type(4)));
typedef float f32x16 __attribute__((ext_vector_type(16)));
typedef unsigned uint4v __attribute__((ext_vector_type(4)));

__device__ __forceinline__ void gload_lds16(const void* g, void* l) {
    __builtin_amdgcn_global_load_lds(
        (const __attribute__((address_space(1))) void*)g,
        (__attribute__((address_space(3))) void*)l, 16, 0, 0);
}

// ---------------- megacast: x + 4 weights -> fp16, bias concat (one launch) ----------------
__global__ __launch_bounds__(256) void megacast(const float* __restrict__ x,
                                                const float* __restrict__ w0,
                                                const float* __restrict__ w1,
                                                const float* __restrict__ w2,
                                                const float* __restrict__ w3,
                                                const float* __restrict__ b0,
                                                const float* __restrict__ b1,
                                                const float* __restrict__ b2,
                                                half_t* __restrict__ xh,
                                                half_t* __restrict__ wc,
                                                float* __restrict__ bc) {
    const int tid = blockIdx.x * blockDim.x + threadIdx.x;
    if (tid < 2304) bc[tid] = tid < 768 ? b0[tid] : tid < 1536 ? b1[tid - 768] : b2[tid - 1536];
    const int stride = gridDim.x * blockDim.x;
    for (long i = tid; i < 2162688; i += stride) {          // float4 elements
        const float* s;
        half_t* d;
        long off;
        if (i < 1572864) { s = x; d = xh; off = i; }        // x: 8192*768/4
        else {
            const long j = i - 1572864;
            const int which = (int)(j / 147456);            // 768*768/4
            off = j - (long)which * 147456;
            s = which == 0 ? w0 : which == 1 ? w1 : which == 2 ? w2 : w3;
            d = wc + (long)which * 589824;
        }
        const float4 v = *(const float4*)(s + off * 4);
        half4_t h = {(half_t)v.x, (half_t)v.y, (half_t)v.z, (half_t)v.w};
        *(half4_t*)(d + off * 4) = h;
    }
}

// ---------------- GEMM: 128x128 tile, BK=64, 2-buf, 2-deep prefetch (r9-proven) ----------------
// C[8192,N] = A[8192,768] * W[N,768]^T + bias.  K=768 (NT=12).
// 64 KiB LDS double-buffer -> 2 blocks/CU; 2-tile-deep global_load_lds
// prefetch with s_waitcnt vmcnt(8); raw s_barrier; XOR-chunk swizzle both
// sides; measured 45 us / 0 bank conflicts (round 9).
// VSPLIT: N-tiles >=12 (= V) written TRANSPOSED into Vt with the PV
// permutation baked in (n bits 2<->3 swapped) so attention reads V as b128.
template <typename OutT, bool VSPLIT>
__global__ __launch_bounds__(256) void gemm128(const half_t* __restrict__ A,
                                               const half_t* __restrict__ W,
                                               const float* __restrict__ bias,
                                               OutT* __restrict__ C,
                                               half_t* __restrict__ Vt,
                                               const int N) {
    constexpr int Kdim = 768, NT = 12;
    alignas(16) __shared__ half_t Ah[2][128 * 64];
    alignas(16) __shared__ half_t Wh[2][128 * 64];

    const int t = threadIdx.x, l = t & 63, wv = t >> 6;
    const int wr = wv >> 1, wc = wv & 1;                 // 2M x 2N waves
    const int m0 = blockIdx.x * 128, n0 = blockIdx.y * 128;

    f32x4 acc[4][4] = {};

    const int srow_g = wv * 8 + (l >> 3);                // 0..31
    const int schunk = l & 7;

    const half_t* Ag = A + (long)m0 * Kdim;
    const half_t* Wg = W + (long)n0 * Kdim;

    auto STAGE = [&](int tile, int buf) {
        const int k0 = tile * 64;
#pragma unroll
        for (int g = 0; g < 4; ++g) {                    // 4 x 32 rows
            const int row = g * 32 + srow_g;
            const int sc_ = (schunk ^ (row & 7)) * 8;
            gload_lds16(Ag + (long)row * Kdim + k0 + sc_,
                        &Ah[buf][(g * 32 + wv * 8) * 64]);
            gload_lds16(Wg + (long)row * Kdim + k0 + sc_,
                        &Wh[buf][(g * 32 + wv * 8) * 64]);
        }
    };

    STAGE(0, 0);
    STAGE(1, 1);

    for (int tt = 0; tt < NT; ++tt) {
        const int buf = tt & 1;
        if (tt < NT - 1) {
            asm volatile("s_waitcnt vmcnt(8)" ::: "memory");
        } else {
            asm volatile("s_waitcnt vmcnt(0)" ::: "memory");
        }
        __builtin_amdgcn_s_barrier();
        asm volatile("" ::: "memory");

#pragma unroll
        for (int ks = 0; ks < 2; ++ks) {
            // K=32 sub-step ks: lane k = ks*32 + (l>>4)*8 -> 16B-chunk ks*4 + (l>>4)
            const int kc = ks * 4 + (l >> 4);
            half8 afr[4], bfr[4];
#pragma unroll
            for (int i = 0; i < 4; ++i) {
                const int arow = wr * 64 + i * 16 + (l & 15);
                afr[i] = *(const half8*)&Ah[buf][arow * 64 + (kc ^ (arow & 7)) * 8];
                const int brow = wc * 64 + i * 16 + (l & 15);
                bfr[i] = *(const half8*)&Wh[buf][brow * 64 + (kc ^ (brow & 7)) * 8];
            }
            __builtin_amdgcn_s_setprio(1);
#pragma unroll
            for (int mi = 0; mi < 4; ++mi)
#pragma unroll
                for (int ni = 0; ni < 4; ++ni)
                    acc[mi][ni] = __builtin_amdgcn_mfma_f32_16x16x32_f16(
                        afr[mi], bfr[ni], acc[mi][ni], 0, 0, 0);
            __builtin_amdgcn_s_setprio(0);
        }

        asm volatile("" ::: "memory");
        __builtin_amdgcn_s_barrier();
        if (tt + 2 < NT) STAGE(tt + 2, buf);
    }

    // ---- epilogue ----
    const bool vtile = VSPLIT && (blockIdx.y >= 12);     // pure-V N-tiles
#pragma unroll
    for (int ni = 0; ni < 4; ++ni) {
        const int col = n0 + wc * 64 + ni * 16 + (l & 15);
        const float bb = bias[col];
        if (!vtile) {
#pragma unroll
            for (int mi = 0; mi < 4; ++mi) {
                const int row = m0 + wr * 64 + mi * 16 + (l >> 4) * 4;
#pragma unroll
                for (int r = 0; r < 4; ++r)
                    C[(long)(row + r) * N + col] = (OutT)(acc[mi][ni][r] + bb);
            }
        } else {
            const int hd = col - 1536;
            const int hidx = hd >> 6, d = hd & 63;
#pragma unroll
            for (int mi = 0; mi < 4; ++mi) {
                const int row = m0 + wr * 64 + mi * 16 + (l >> 4) * 4;
                const int b = row >> 10, n = row & 1023;
                // bake PV permutation: swap bits 2<->3 of n (quad-aligned, bijective)
                const int np = (n & ~12) | ((n & 4) << 1) | ((n & 8) >> 1);
                half4_t pk;
#pragma unroll
                for (int r = 0; r < 4; ++r) pk[r] = (half_t)(acc[mi][ni][r] + bb);
                *(half4_t*)(Vt + ((long)((b * 12 + hidx) * 64 + d)) * 1024 + np) = pk;
            }
        }
    }
}

// ---------------- flash attention v6 (validated round 13) ----------------
__global__ __launch_bounds__(256) void attn6_kernel(const half_t* __restrict__ qkv,
                                                    const half_t* __restrict__ Vt,
                                                    const float* __restrict__ head_mask,
                                                    half_t* __restrict__ Y) {
    alignas(16) __shared__ half_t Kl[2][64 * 64];
    alignas(16) __shared__ half_t Vl[2][64 * 64];

    const int t = threadIdx.x, l = t & 63, wv = t >> 6;
    const int h2 = l >> 5, q32 = l & 31;
    const int bh = blockIdx.x, b = bh / 12, hh = bh % 12;
    const int q0 = blockIdx.y * 128 + wv * 32;

    half8 qf[4];
    {
        const half_t SC = (half_t)(0.125f * 1.44269504f);
        const half_t* Qp = qkv + ((long)(b * 1024 + q0 + q32)) * 2304 + hh * 64 + h2 * 8;
#pragma unroll
        for (int kd = 0; kd < 4; ++kd) {
            half8 v = *(const half8*)(Qp + kd * 16);
#pragma unroll
            for (int j = 0; j < 8; ++j) v[j] = v[j] * SC;
            qf[kd] = v;
        }
    }

    const half8 ONES = {(half_t)1, (half_t)1, (half_t)1, (half_t)1,
                        (half_t)1, (half_t)1, (half_t)1, (half_t)1};

    const half_t* Kg = qkv + (long)b * 1024 * 2304 + 768 + hh * 64;
    const half_t* Vg = Vt + (long)bh * 64 * 1024;

    const int srow_lo = (l >> 3);
    const int schunk = l & 7;

    auto STAGE = [&](int tile, int bf) {
#pragma unroll
        for (int c = 0; c < 2; ++c) {
            const int row = c * 32 + wv * 8 + srow_lo;
            const int sc_ = (schunk ^ (row & 7)) * 8;
            gload_lds16(Kg + (long)(tile * 64 + row) * 2304 + sc_,
                        &Kl[bf][(c * 32 + wv * 8) * 64]);
            gload_lds16(Vg + (long)row * 1024 + tile * 64 + sc_,
                        &Vl[bf][(c * 32 + wv * 8) * 64]);
        }
    };

    f32x16 o0 = {}, o1 = {}, lacc = {};

    STAGE(0, 0);

    for (int tt = 0; tt < 16; ++tt) {
        const int bf = tt & 1;
        if (tt < 15) {
            STAGE(tt + 1, bf ^ 1);
            asm volatile("s_waitcnt vmcnt(4)" ::: "memory");
        } else {
            asm volatile("s_waitcnt vmcnt(0)" ::: "memory");
        }
        __builtin_amdgcn_s_barrier();
        asm volatile("" ::: "memory");

        f32x16 s0 = {}, s1 = {};
        __builtin_amdgcn_s_setprio(1);
#pragma unroll
        for (int kd = 0; kd < 4; ++kd) {
            const int ch = ((kd * 2 + h2) ^ (q32 & 7)) * 8;
            half8 k0 = *(const half8*)&Kl[bf][q32 * 64 + ch];
            half8 k1 = *(const half8*)&Kl[bf][(32 + q32) * 64 + ch];
            s0 = __builtin_amdgcn_mfma_f32_32x32x16_f16(k0, qf[kd], s0, 0, 0, 0);
            s1 = __builtin_amdgcn_mfma_f32_32x32x16_f16(k1, qf[kd], s1, 0, 0, 0);
        }
        __builtin_amdgcn_s_setprio(0);

#pragma unroll
        for (int kc = 0; kc < 4; ++kc) {
            const f32x16& ss = (kc >> 1) ? s1 : s0;
            const int rb = (kc & 1) * 8;
            unsigned pw[4];
#pragma unroll
            for (int k2 = 0; k2 < 4; ++k2) {
                const float a = __builtin_amdgcn_exp2f(ss[rb + 2 * k2]);
                const float c = __builtin_amdgcn_exp2f(ss[rb + 2 * k2 + 1]);
                pw[k2] = __builtin_bit_cast(unsigned, __builtin_amdgcn_cvt_pkrtz(a, c));
            }
            uint4v uu = {pw[0], pw[1], pw[2], pw[3]};
            const half8 pf = __builtin_bit_cast(half8, uu);

            // V fragment: single b128 per row (permuted layout baked in Vt)
            const int ch = ((2 * kc + h2) ^ (q32 & 7)) * 8;
            half8 vf0 = *(const half8*)&Vl[bf][q32 * 64 + ch];
            half8 vf1 = *(const half8*)&Vl[bf][(32 + q32) * 64 + ch];

            __builtin_amdgcn_s_setprio(1);
            o0 = __builtin_amdgcn_mfma_f32_32x32x16_f16(vf0, pf, o0, 0, 0, 0);
            o1 = __builtin_amdgcn_mfma_f32_32x32x16_f16(vf1, pf, o1, 0, 0, 0);
            lacc = __builtin_amdgcn_mfma_f32_32x32x16_f16(ONES, pf, lacc, 0, 0, 0);
            __builtin_amdgcn_s_setprio(0);
        }

        asm volatile("" ::: "memory");
        __builtin_amdgcn_s_barrier();
    }

    const float hmv = head_mask[b * 12 + hh];
    const float sc = hmv * hmv / lacc[0];
    half_t* Yp = Y + ((long)(b * 1024 + q0 + q32)) * 768 + hh * 64;
#pragma unroll
    for (int db = 0; db < 2; ++db) {
        const f32x16 oo = db ? o1 : o0;
#pragma unroll
        for (int rq = 0; rq < 4; ++rq) {
            half4_t pk;
#pragma unroll
            for (int i = 0; i < 4; ++i) pk[i] = (half_t)(oo[rq * 4 + i] * sc);
            *(half4_t*)(Yp + db * 32 + rq * 8 + h2 * 4) = pk;
        }
    }
}

// ---------------- launch ----------------
extern "C" void kernel_launch(void* const* d_in, const int* in_sizes, int n_in,
                              void* d_out, int out_size, void* d_ws, size_t ws_size,
                              hipStream_t stream) {
    const float* x   = (const float*)d_in[0];
    const float* hm  = (const float*)d_in[1];
    const float* q_w = (const float*)d_in[2];
    const float* q_b = (const float*)d_in[3];
    const float* k_w = (const float*)d_in[4];
    const float* k_b = (const float*)d_in[5];
    const float* v_w = (const float*)d_in[6];
    const float* v_b = (const float*)d_in[7];
    const float* p_w = (const float*)d_in[8];
    const float* p_b = (const float*)d_in[9];
    float* out = (float*)d_out;

    char* ws = (char*)d_ws;
    half_t* xh  = (half_t*)(ws);                    // 8192*768*2   = 12582912
    half_t* wc  = (half_t*)(ws + 12582912);         // [q|k|v|p] weights fp16
    half_t* pwh = (half_t*)(ws + 16121856);         //   (proj part of wc)
    float*  bc  = (float*)(ws + 17301504);          // 2304*4
    half_t* qkv = (half_t*)(ws + 17310720);         // 8192*2304*2  = 37748736
    half_t* y   = (half_t*)(ws + 55059456);         // 8192*768*2   = 12582912
    half_t* Vt = (ws_size >= (size_t)67642368 + 12582912)
                     ? (half_t*)(ws + 67642368)
                     : (half_t*)d_out;

    megacast<<<2048, 256, 0, stream>>>(x, q_w, k_w, v_w, p_w, q_b, k_b, v_b, xh, wc, bc);

    gemm128<half_t, true><<<dim3(64, 18), 256, 0, stream>>>(xh, wc, bc, qkv, Vt, 2304);
    attn6_kernel<<<dim3(96, 8), 256, 0, stream>>>(qkv, Vt, hm, y);
    gemm128<float, false><<<dim3(64, 6), 256, 0, stream>>>(y, pwh, p_b, out, nullptr, 768);
}